// Round 19
// baseline (113.695 us; speedup 1.0000x reference)
//
#include <hip/hip_runtime.h>

#define NNODES 10000
#define NEDGES 160000
#define NB 8
#define NC 32
#define CAP 96        // slots per node bucket (deg clamp 72; Poisson(16) tail ~1e-25)
#define LUTB 2048
#define EBLKS 625     // NEDGES/256 exactly
#define LUTBLKS 128   // 2*LUTB*8 uint2 entries / 256
#define HALFN 5000    // dual-node gather: wave wid owns nodes (wid, wid+HALFN)
#define GBLKS 1250    // HALFN/4 waves per block
constexpr float NEG_SLOPE = 0.01f;

__device__ __forceinline__ float sigmoidf_(float x) {
    return 1.0f / (1.0f + __expf(-x));
}

// pack two f32 -> one u32 holding bf16(a) in low16, bf16(b) in high16 (RNE)
__device__ __forceinline__ unsigned pk2bf(float a, float b) {
    unsigned ua = __float_as_uint(a);
    ua = (ua + 0x7fffu + ((ua >> 16) & 1u)) >> 16;
    unsigned ub = __float_as_uint(b);
    ub = (ub + 0x7fffu + ((ub >> 16) & 1u)) & 0xffff0000u;
    return ua | ub;
}

// ---- K1 (single prologue kernel; all block roles independent) ----
// [0, 2*EBLKS)        : edge scatter -> fixed-cap buckets, payload (src|ix<<14, w*ce+ab)
// [2E, 2E+LUTBLKS)    : bf16 sige LUT fill + zero xs sentinel rows
// 2E+LUTBLKS          : consts fold ([64:96) aq2, [96:128) ak2)
// rest (NNODES/4)     : layer-1 node transform -> bf16 xs1 (inline aq/ak fold)
// cnt (2*NNODES ints) must be zeroed before this kernel.
__global__ __launch_bounds__(256) void prologue_kernel(
    const float* Q1, const float* K1, const float* aw1, const float* We1,
    const float* Q2, const float* K2, const float* aw2, const float* We2,
    const int* __restrict__ ei0, const int* __restrict__ ei1,
    const float* __restrict__ ew0, const float* __restrict__ ew1,
    const float* __restrict__ ab1, const float* __restrict__ ab2,
    float* consts, uint2* __restrict__ lut,
    int2* __restrict__ pkw1, int2* __restrict__ pkw2,
    int* __restrict__ cnt,
    unsigned* __restrict__ xs1h, unsigned* __restrict__ xs2h,
    float* __restrict__ sq1, float* __restrict__ sk1,
    const float* __restrict__ X, const float* __restrict__ Wn)
{
    int bx = blockIdx.x;
    int t = threadIdx.x;

    if (bx < 2 * EBLKS) {                       // scatter (NEDGES % 256 == 0: no tail)
        __shared__ float sCE, sAB;
        int layer = bx / EBLKS;
        int e = (bx % EBLKS) * 256 + t;
        const int*   ei = layer ? ei1 : ei0;
        const float* ew = layer ? ew1 : ew0;
        int src = ei[e];
        int dst = ei[NEDGES + e];
        float w = ew[e];
        if (t < 32) {                           // per-block ce = We . aw[64:96], ab
            const float* We = layer ? We2 : We1;
            const float* aw = layer ? aw2 : aw1;
            float p = We[t] * aw[64 + t];
            #pragma unroll
            for (int m = 16; m >= 1; m >>= 1) p += __shfl_xor(p, m, 32);
            if (t == 0) { sCE = p; sAB = (layer ? ab2 : ab1)[0]; }
        }
        __syncthreads();
        int pos = atomicAdd(&cnt[layer * NNODES + dst], 1);
        if (pos < CAP) {
            int ix = (int)(w * (float)LUTB);
            ix = min(max(ix, 0), LUTB - 1);
            (layer ? pkw2 : pkw1)[(size_t)dst * CAP + pos] =
                make_int2(src | (ix << 14), __float_as_int(w * sCE + sAB));
        }
        return;
    }
    if (bx < 2 * EBLKS + LUTBLKS) {             // bf16 sige LUT [2][2048][8 uint2]
        int i = (bx - 2 * EBLKS) * 256 + t;     // uint2 entry index
        int layer = i >> 14;                    // LUTB*8 = 16384
        int bin   = (i >> 3) & (LUTB - 1);
        int o4    = i & 7;
        float w   = (bin + 0.5f) * (1.0f / LUTB);
        const float* We = layer ? We2 : We1;
        float s0 = sigmoidf_(w * We[o4 * 4 + 0]);
        float s1 = sigmoidf_(w * We[o4 * 4 + 1]);
        float s2 = sigmoidf_(w * We[o4 * 4 + 2]);
        float s3 = sigmoidf_(w * We[o4 * 4 + 3]);
        lut[i] = make_uint2(pk2bf(s0, s1), pk2bf(s2, s3));
        if (i < 128) {                          // zero bf16 xs sentinel rows (row NNODES)
            xs1h[(size_t)NNODES * 128 + i] = 0u;
            xs2h[(size_t)NNODES * 128 + i] = 0u;
        }
        return;
    }
    if (bx == 2 * EBLKS + LUTBLKS) {            // consts fold (layer-2 aq/ak only)
        if (t < 32) {
            float aq2 = 0.f, ak2 = 0.f;
            for (int s = 0; s < 32; ++s) {
                aq2 += Q2[t * 32 + s] * aw2[s];
                ak2 += K2[t * 32 + s] * aw2[32 + s];
            }
            consts[64 + t] = aq2;
            consts[96 + t] = ak2;
        }
        return;
    }

    // node transform: xs1h = bf16(X @ Wn) ; sq1 = xs.aq ; sk1 = xs.ak (X is [B,N,C])
    __shared__ float wnL[NC * NC];
    __shared__ float aqL[NC], akL[NC];
    __shared__ float xrow[4][NB][NC + 4];
    int w = t >> 6, l = t & 63, b = l >> 3, o4 = l & 7;
    int n = (bx - (2 * EBLKS + LUTBLKS + 1)) * 4 + w;
    for (int i = t; i < NC * NC; i += 256) wnL[i] = Wn[i];
    if (t < 64) {                               // inline aq/ak fold (no cross-block dep)
        int which = t >> 5, o = t & 31;
        const float* M  = which ? K1 : Q1;
        const float* av = aw1 + which * 32;
        float s = 0.f;
        for (int k = 0; k < 32; ++k) s += M[o * 32 + k] * av[k];
        (which ? akL : aqL)[o] = s;
    }
    const float4* X4 = (const float4*)X;
    float4 xv = X4[((size_t)b * NNODES + n) * 8 + o4];
    ((float4*)&xrow[w][b][0])[o4] = xv;
    __syncthreads();
    float4 aq = ((const float4*)aqL)[o4];
    float4 ak = ((const float4*)akL)[o4];
    const float4* wnL4 = (const float4*)wnL;
    float4 acc = {0.f, 0.f, 0.f, 0.f};
    #pragma unroll
    for (int c = 0; c < NC; ++c) {
        float xc = xrow[w][b][c];
        float4 w4 = wnL4[c * 8 + o4];
        acc.x += xc * w4.x; acc.y += xc * w4.y;
        acc.z += xc * w4.z; acc.w += xc * w4.w;
    }
    ((uint2*)xs1h)[(size_t)n * 64 + l] = make_uint2(pk2bf(acc.x, acc.y), pk2bf(acc.z, acc.w));
    float vq = acc.x * aq.x + acc.y * aq.y + acc.z * aq.z + acc.w * aq.w;
    float vk = acc.x * ak.x + acc.y * ak.y + acc.z * ak.z + acc.w * ak.w;
    #pragma unroll
    for (int m = 4; m >= 1; m >>= 1) {
        vq += __shfl_xor(vq, m);
        vk += __shfl_xor(vk, m);
    }
    if (o4 == 0) {
        sq1[n * NB + b] = vq;
        sk1[n * NB + b] = vk;
    }
}

// DUAL-NODE gather: 1250 blocks x 4 waves; wave wid owns nodes (wid, wid+HALFN),
// chunk loops INTERLEAVED j-by-j -> 2x outstanding loads per wave at the same
// 4-waves/SIMD occupancy (lean uint2 payloads keep VGPR in the 65-128 class;
// R11's f32 dual-node hit 164 VGPR -> 2 waves/SIMD, this is the lean retry).
// Lane = (b = l>>3, o4 = l&7). bf16 xs + bf16 LUT, LDS-staged epilogue,
// NaN-safe per-node sentinel masking; loop runs to max(degA, degB).
// MODE 0: fuse layer-2 node transform (bf16 xs2). MODE 1: final output [B,N,C] f32.
template <int MODE>
__global__ __launch_bounds__(256) void gather_kernel(
    const int* __restrict__ cnt, const int2* __restrict__ pkw,
    const unsigned* __restrict__ xsh,
    const float* __restrict__ sq, const float* __restrict__ sk,
    const uint2* __restrict__ luth,
    const float* __restrict__ consts,
    const float* __restrict__ ow, const float* __restrict__ ob,
    const float* __restrict__ Wn2,
    unsigned* __restrict__ xs2h, float* __restrict__ sq2, float* __restrict__ sk2,
    float* __restrict__ outp)
{
    __shared__ __align__(16) float owL[2 * NC * NC];                 // 8 KB
    __shared__ __align__(16) float wnL[(MODE == 0) ? NC * NC : 4];   // 4 KB (MODE 0)
    __shared__ __align__(16) float xL[4][NB][NC];                    // 4 KB (per-wave slices)
    __shared__ __align__(16) float aL[4][NB][NC];                    // 4 KB

    int t = threadIdx.x, w = t >> 6, l = t & 63, b = l >> 3, o4 = l & 7;
    int wid = blockIdx.x * 4 + w;
    int nA = wid, nB = wid + HALFN;
    for (int i = t; i < 2 * NC * NC; i += 256) owL[i] = ow[i];
    if (MODE == 0)
        for (int i = t; i < NC * NC; i += 256) wnL[i] = Wn2[i];
    __syncthreads();   // only barrier (weight staging)

    const float4* owL4 = (const float4*)owL;
    const float4* wnL4 = (const float4*)wnL;
    const uint2*  XH   = (const uint2*)xsh;

    // both nodes' independent startup loads issue together
    int degA = min(cnt[nA], CAP - 24);
    int degB = min(cnt[nB], CAP - 24);
    const int2* ppA = pkw + (size_t)nA * CAP;
    const int2* ppB = pkw + (size_t)nB * CAP;
    int2  mcA  = ppA[o4];
    int2  mcB  = ppB[o4];
    float skbA = sk[nA * NB + b];
    float skbB = sk[nB * NB + b];
    float sqA  = sq[(mcA.x & 16383) * NB + b];  // dependent hops, also paired
    float sqB  = sq[(mcB.x & 16383) * NB + b];

    float4 accA = {0.f, 0.f, 0.f, 0.f};
    float4 accB = {0.f, 0.f, 0.f, 0.f};
    int maxc = max(degA, degB);
    for (int c0 = 0; c0 < maxc; c0 += 8) {
        // unconditional prefetch for both nodes (CAP=96 keeps c0+8+o4 <= 79 in-bucket)
        int2 mnA = ppA[c0 + 8 + o4];
        int2 mnB = ppB[c0 + 8 + o4];
        float sqnA = sq[(mnA.x & 16383) * NB + b];
        float sqnB = sq[(mnB.x & 16383) * NB + b];
        float attA = (c0 + o4 < degA)
                   ? sigmoidf_(sqA + skbA + __int_as_float(mcA.y)) : 0.f;
        float attB = (c0 + o4 < degB)
                   ? sigmoidf_(sqB + skbB + __int_as_float(mcB.y)) : 0.f;
        #pragma unroll
        for (int j = 0; j < 8; ++j) {
            int spkA = __builtin_amdgcn_readlane(mcA.x, j);     // SGPR metadata
            int spkB = __builtin_amdgcn_readlane(mcB.x, j);
            int ssA, sixA, ssB, sixB;
            if (c0 + j < degA) { ssA = spkA & 16383; sixA = (spkA >> 14) & 2047; }
            else               { ssA = NNODES;       sixA = 0; }
            if (c0 + j < degB) { ssB = spkB & 16383; sixB = (spkB >> 14) & 2047; }
            else               { ssB = NNODES;       sixB = 0; }
            uint2 hxA = XH[(size_t)ssA * 64 + l];
            uint2 hgA = luth[sixA * 8 + o4];
            uint2 hxB = XH[(size_t)ssB * 64 + l];
            uint2 hgB = luth[sixB * 8 + o4];
            float atA = __shfl(attA, b * 8 + j);
            float atB = __shfl(attB, b * 8 + j);
            accA.x += atA * __uint_as_float(hgA.x << 16)         * __uint_as_float(hxA.x << 16);
            accA.y += atA * __uint_as_float(hgA.x & 0xffff0000u) * __uint_as_float(hxA.x & 0xffff0000u);
            accA.z += atA * __uint_as_float(hgA.y << 16)         * __uint_as_float(hxA.y << 16);
            accA.w += atA * __uint_as_float(hgA.y & 0xffff0000u) * __uint_as_float(hxA.y & 0xffff0000u);
            accB.x += atB * __uint_as_float(hgB.x << 16)         * __uint_as_float(hxB.x << 16);
            accB.y += atB * __uint_as_float(hgB.x & 0xffff0000u) * __uint_as_float(hxB.x & 0xffff0000u);
            accB.z += atB * __uint_as_float(hgB.y << 16)         * __uint_as_float(hxB.y << 16);
            accB.w += atB * __uint_as_float(hgB.y & 0xffff0000u) * __uint_as_float(hxB.y & 0xffff0000u);
        }
        mcA = mnA; sqA = sqnA;
        mcB = mnB; sqB = sqnB;
    }

    // epilogue x2 (sequential, LDS slices reused; i is compile-time in unrolled loop)
    #pragma unroll
    for (int i = 0; i < 2; ++i) {
        int n = i ? nB : nA;
        float4 acc = i ? accB : accA;
        uint2 hv = XH[(size_t)n * 64 + l];
        float4 xv;
        xv.x = __uint_as_float(hv.x << 16);
        xv.y = __uint_as_float(hv.x & 0xffff0000u);
        xv.z = __uint_as_float(hv.y << 16);
        xv.w = __uint_as_float(hv.y & 0xffff0000u);
        ((float4*)&xL[w][b][0])[o4] = xv;
        ((float4*)&aL[w][b][0])[o4] = acc;
        float4 u = ((const float4*)ob)[o4];
        #pragma unroll 4
        for (int c = 0; c < NC; ++c) {
            float xc = xL[w][b][c];
            float ac = aL[w][b][c];
            float4 w1 = owL4[c * 8 + o4];
            float4 w2 = owL4[(NC + c) * 8 + o4];
            u.x += xc * w1.x + ac * w2.x;
            u.y += xc * w1.y + ac * w2.y;
            u.z += xc * w1.z + ac * w2.z;
            u.w += xc * w1.w + ac * w2.w;
        }
        float4 r;
        r.x = xv.x + u.x; r.y = xv.y + u.y; r.z = xv.z + u.z; r.w = xv.w + u.w;
        r.x = (r.x > 0.f) ? r.x : NEG_SLOPE * r.x;
        r.y = (r.y > 0.f) ? r.y : NEG_SLOPE * r.y;
        r.z = (r.z > 0.f) ? r.z : NEG_SLOPE * r.z;
        r.w = (r.w > 0.f) ? r.w : NEG_SLOPE * r.w;

        if (MODE == 1) {
            ((float4*)outp)[((size_t)b * NNODES + n) * 8 + o4] = r;
        } else {
            // fused layer-2 node transform: xs2h = bf16(h @ Wn2) ; sq2, sk2 (f32)
            ((float4*)&xL[w][b][0])[o4] = r;    // reuse slice (wave-local)
            float4 a2 = {0.f, 0.f, 0.f, 0.f};
            #pragma unroll 4
            for (int c = 0; c < NC; ++c) {
                float hc = xL[w][b][c];
                float4 w0 = wnL4[c * 8 + o4];
                a2.x += hc * w0.x;
                a2.y += hc * w0.y;
                a2.z += hc * w0.z;
                a2.w += hc * w0.w;
            }
            ((uint2*)xs2h)[(size_t)n * 64 + l] = make_uint2(pk2bf(a2.x, a2.y), pk2bf(a2.z, a2.w));
            float4 aqv = ((const float4*)(consts + 64))[o4];
            float4 akv = ((const float4*)(consts + 96))[o4];
            float vq = a2.x*aqv.x + a2.y*aqv.y + a2.z*aqv.z + a2.w*aqv.w;
            float vk = a2.x*akv.x + a2.y*akv.y + a2.z*akv.z + a2.w*akv.w;
            #pragma unroll
            for (int m = 4; m >= 1; m >>= 1) {
                vq += __shfl_xor(vq, m);
                vk += __shfl_xor(vk, m);
            }
            if (o4 == 0) {
                sq2[n * NB + b] = vq;
                sk2[n * NB + b] = vk;
            }
        }
    }
}

extern "C" void kernel_launch(void* const* d_in, const int* in_sizes, int n_in,
                              void* d_out, int out_size, void* d_ws, size_t ws_size,
                              hipStream_t stream) {
    const float* X    = (const float*)d_in[0];
    const int*   ei0  = (const int*)  d_in[1];
    const int*   ei1  = (const int*)  d_in[2];
    const float* ew0  = (const float*)d_in[3];
    const float* ew1  = (const float*)d_in[4];
    const float* Wn1  = (const float*)d_in[7];
    const float* We1  = (const float*)d_in[8];
    const float* Q1   = (const float*)d_in[9];
    const float* K1   = (const float*)d_in[10];
    const float* aw1  = (const float*)d_in[11];
    const float* ab1  = (const float*)d_in[12];
    const float* ow1  = (const float*)d_in[13];
    const float* ob1  = (const float*)d_in[14];
    const float* Wn2  = (const float*)d_in[15];
    const float* We2  = (const float*)d_in[16];
    const float* Q2   = (const float*)d_in[17];
    const float* K2   = (const float*)d_in[18];
    const float* aw2  = (const float*)d_in[19];
    const float* ab2  = (const float*)d_in[20];
    const float* ow2  = (const float*)d_in[21];
    const float* ob2  = (const float*)d_in[22];

    const size_t ROWH = (size_t)(NNODES + 1) * 128;      // u32 words per bf16 xs buffer
    const size_t SS   = (size_t)(NNODES + 1) * NB;       // 80,008
    unsigned* XS1H  = (unsigned*)d_ws;
    unsigned* XS2H  = XS1H + ROWH;
    float* SQ1    = (float*)(XS2H + ROWH);
    float* SK1    = SQ1 + SS;
    float* SQ2    = SK1 + SS;
    float* SK2    = SQ2 + SS;
    float* CONSTS = SK2 + SS;                            // 160
    uint2* LUTH   = (uint2*)(CONSTS + 160);              // 2*LUTB*8 uint2 (256 KB)
    int*   CNT    = (int*)(LUTH + 2 * LUTB * 8);         // 2*N
    int2*  PKW1   = (int2*)(CNT + 2 * NNODES);
    int2*  PKW2   = PKW1 + (size_t)NNODES * CAP;

    hipMemsetAsync(CNT, 0, 2 * NNODES * sizeof(int), stream);
    prologue_kernel<<<2 * EBLKS + LUTBLKS + 1 + NNODES / 4, 256, 0, stream>>>(
        Q1, K1, aw1, We1, Q2, K2, aw2, We2, ei0, ei1, ew0, ew1, ab1, ab2,
        CONSTS, LUTH, PKW1, PKW2, CNT, XS1H, XS2H, SQ1, SK1, X, Wn1);

    gather_kernel<0><<<GBLKS, 256, 0, stream>>>(
        CNT, PKW1, XS1H, SQ1, SK1, LUTH, CONSTS,
        ow1, ob1, Wn2, XS2H, SQ2, SK2, nullptr);
    gather_kernel<1><<<GBLKS, 256, 0, stream>>>(
        CNT + NNODES, PKW2, XS2H, SQ2, SK2, LUTH + LUTB * 8, CONSTS,
        ow2, ob2, nullptr, nullptr, nullptr, nullptr, (float*)d_out);
}

// Round 20
// 88.868 us; speedup vs baseline: 1.2794x; 1.2794x over previous
//
#include <hip/hip_runtime.h>

#define NNODES 10000
#define NEDGES 160000
#define NB 8
#define NC 32
#define NCP 36        // padded LDS row stride (floats): bank(b*36+c) spreads b-groups
#define CAP 96        // slots per node bucket (deg clamp 72; Poisson(16) tail ~1e-25)
#define LUTB 2048
#define EBLKS 625     // NEDGES/256 exactly
#define LUTBLKS 128   // 2*LUTB*8 uint2 entries / 256
#define NWAVES 4000   // gather waves (1000 blocks x 4); ~4 waves/SIMD resident
#define KNODES 3      // nodes per wave, software-pipelined
constexpr float NEG_SLOPE = 0.01f;

__device__ __forceinline__ float sigmoidf_(float x) {
    return 1.0f / (1.0f + __expf(-x));
}

// pack two f32 -> one u32 holding bf16(a) in low16, bf16(b) in high16 (RNE)
__device__ __forceinline__ unsigned pk2bf(float a, float b) {
    unsigned ua = __float_as_uint(a);
    ua = (ua + 0x7fffu + ((ua >> 16) & 1u)) >> 16;
    unsigned ub = __float_as_uint(b);
    ub = (ub + 0x7fffu + ((ub >> 16) & 1u)) & 0xffff0000u;
    return ua | ub;
}

// ---- K1 (single prologue kernel; all block roles independent) ----
// [0, 2*EBLKS)        : edge scatter -> fixed-cap buckets, payload (src|ix<<14, w*ce+ab)
// [2E, 2E+LUTBLKS)    : bf16 sige LUT fill + zero xs sentinel rows
// 2E+LUTBLKS          : consts fold ([64:96) aq2, [96:128) ak2)
// rest (NNODES/4)     : layer-1 node transform -> bf16 xs1 (inline aq/ak fold)
// cnt (2*NNODES ints) must be zeroed before this kernel.
__global__ __launch_bounds__(256) void prologue_kernel(
    const float* Q1, const float* K1, const float* aw1, const float* We1,
    const float* Q2, const float* K2, const float* aw2, const float* We2,
    const int* __restrict__ ei0, const int* __restrict__ ei1,
    const float* __restrict__ ew0, const float* __restrict__ ew1,
    const float* __restrict__ ab1, const float* __restrict__ ab2,
    float* consts, uint2* __restrict__ lut,
    int2* __restrict__ pkw1, int2* __restrict__ pkw2,
    int* __restrict__ cnt,
    unsigned* __restrict__ xs1h, unsigned* __restrict__ xs2h,
    float* __restrict__ sq1, float* __restrict__ sk1,
    const float* __restrict__ X, const float* __restrict__ Wn)
{
    int bx = blockIdx.x;
    int t = threadIdx.x;

    if (bx < 2 * EBLKS) {                       // scatter (NEDGES % 256 == 0: no tail)
        __shared__ float sCE, sAB;
        int layer = bx / EBLKS;
        int e = (bx % EBLKS) * 256 + t;
        const int*   ei = layer ? ei1 : ei0;
        const float* ew = layer ? ew1 : ew0;
        int src = ei[e];
        int dst = ei[NEDGES + e];
        float w = ew[e];
        if (t < 32) {                           // per-block ce = We . aw[64:96], ab
            const float* We = layer ? We2 : We1;
            const float* aw = layer ? aw2 : aw1;
            float p = We[t] * aw[64 + t];
            #pragma unroll
            for (int m = 16; m >= 1; m >>= 1) p += __shfl_xor(p, m, 32);
            if (t == 0) { sCE = p; sAB = (layer ? ab2 : ab1)[0]; }
        }
        __syncthreads();
        int pos = atomicAdd(&cnt[layer * NNODES + dst], 1);
        if (pos < CAP) {
            int ix = (int)(w * (float)LUTB);
            ix = min(max(ix, 0), LUTB - 1);
            (layer ? pkw2 : pkw1)[(size_t)dst * CAP + pos] =
                make_int2(src | (ix << 14), __float_as_int(w * sCE + sAB));
        }
        return;
    }
    if (bx < 2 * EBLKS + LUTBLKS) {             // bf16 sige LUT [2][2048][8 uint2]
        int i = (bx - 2 * EBLKS) * 256 + t;     // uint2 entry index
        int layer = i >> 14;                    // LUTB*8 = 16384
        int bin   = (i >> 3) & (LUTB - 1);
        int o4    = i & 7;
        float w   = (bin + 0.5f) * (1.0f / LUTB);
        const float* We = layer ? We2 : We1;
        float s0 = sigmoidf_(w * We[o4 * 4 + 0]);
        float s1 = sigmoidf_(w * We[o4 * 4 + 1]);
        float s2 = sigmoidf_(w * We[o4 * 4 + 2]);
        float s3 = sigmoidf_(w * We[o4 * 4 + 3]);
        lut[i] = make_uint2(pk2bf(s0, s1), pk2bf(s2, s3));
        if (i < 128) {                          // zero bf16 xs sentinel rows (row NNODES)
            xs1h[(size_t)NNODES * 128 + i] = 0u;
            xs2h[(size_t)NNODES * 128 + i] = 0u;
        }
        return;
    }
    if (bx == 2 * EBLKS + LUTBLKS) {            // consts fold (layer-2 aq/ak only)
        if (t < 32) {
            float aq2 = 0.f, ak2 = 0.f;
            for (int s = 0; s < 32; ++s) {
                aq2 += Q2[t * 32 + s] * aw2[s];
                ak2 += K2[t * 32 + s] * aw2[32 + s];
            }
            consts[64 + t] = aq2;
            consts[96 + t] = ak2;
        }
        return;
    }

    // node transform: xs1h = bf16(X @ Wn) ; sq1 = xs.aq ; sk1 = xs.ak (X is [B,N,C])
    __shared__ float wnL[NC * NC];
    __shared__ float aqL[NC], akL[NC];
    __shared__ float xrow[4][NB][NC + 4];
    int w = t >> 6, l = t & 63, b = l >> 3, o4 = l & 7;
    int n = (bx - (2 * EBLKS + LUTBLKS + 1)) * 4 + w;
    for (int i = t; i < NC * NC; i += 256) wnL[i] = Wn[i];
    if (t < 64) {                               // inline aq/ak fold (no cross-block dep)
        int which = t >> 5, o = t & 31;
        const float* M  = which ? K1 : Q1;
        const float* av = aw1 + which * 32;
        float s = 0.f;
        for (int k = 0; k < 32; ++k) s += M[o * 32 + k] * av[k];
        (which ? akL : aqL)[o] = s;
    }
    const float4* X4 = (const float4*)X;
    float4 xv = X4[((size_t)b * NNODES + n) * 8 + o4];
    ((float4*)&xrow[w][b][0])[o4] = xv;
    __syncthreads();
    float4 aq = ((const float4*)aqL)[o4];
    float4 ak = ((const float4*)akL)[o4];
    const float4* wnL4 = (const float4*)wnL;
    float4 acc = {0.f, 0.f, 0.f, 0.f};
    #pragma unroll
    for (int c = 0; c < NC; ++c) {
        float xc = xrow[w][b][c];
        float4 w4 = wnL4[c * 8 + o4];
        acc.x += xc * w4.x; acc.y += xc * w4.y;
        acc.z += xc * w4.z; acc.w += xc * w4.w;
    }
    ((uint2*)xs1h)[(size_t)n * 64 + l] = make_uint2(pk2bf(acc.x, acc.y), pk2bf(acc.z, acc.w));
    float vq = acc.x * aq.x + acc.y * aq.y + acc.z * aq.z + acc.w * aq.w;
    float vk = acc.x * ak.x + acc.y * ak.y + acc.z * ak.z + acc.w * ak.w;
    #pragma unroll
    for (int m = 4; m >= 1; m >>= 1) {
        vq += __shfl_xor(vq, m);
        vk += __shfl_xor(vk, m);
    }
    if (o4 == 0) {
        sq1[n * NB + b] = vq;
        sk1[n * NB + b] = vk;
    }
}

// Gather: 1000 blocks x 4 waves; wave wid handles nodes wid + k*NWAVES (k<KNODES),
// software-pipelined across nodes (R18 structure). LDS epilogue slices padded to
// stride NCP=36 floats: bank(b*36+c) = (4b+c)%32 spreads the 8 b-groups across
// banks -> kills the 8-way epilogue bank conflict measured in R19 (960K cycles).
// Lane = (b = l>>3, o4 = l&7). bf16 xs + bf16 LUT, NaN-safe sentinel masking.
// MODE 0: fuse layer-2 node transform (bf16 xs2). MODE 1: final output [B,N,C] f32.
template <int MODE>
__global__ __launch_bounds__(256) void gather_kernel(
    const int* __restrict__ cnt, const int2* __restrict__ pkw,
    const unsigned* __restrict__ xsh,
    const float* __restrict__ sq, const float* __restrict__ sk,
    const uint2* __restrict__ luth,
    const float* __restrict__ consts,
    const float* __restrict__ ow, const float* __restrict__ ob,
    const float* __restrict__ Wn2,
    unsigned* __restrict__ xs2h, float* __restrict__ sq2, float* __restrict__ sk2,
    float* __restrict__ outp)
{
    __shared__ __align__(16) float owL[2 * NC * NC];                 // 8 KB
    __shared__ __align__(16) float wnL[(MODE == 0) ? NC * NC : 4];   // 4 KB (MODE 0)
    __shared__ __align__(16) float xL[4][NB][NCP];                   // padded slices
    __shared__ __align__(16) float aL[4][NB][NCP];

    int t = threadIdx.x, w = t >> 6, l = t & 63, b = l >> 3, o4 = l & 7;
    int wid = blockIdx.x * 4 + w;
    for (int i = t; i < 2 * NC * NC; i += 256) owL[i] = ow[i];
    if (MODE == 0)
        for (int i = t; i < NC * NC; i += 256) wnL[i] = Wn2[i];
    __syncthreads();   // only barrier (weight staging)

    const float4* owL4 = (const float4*)owL;
    const float4* wnL4 = (const float4*)wnL;
    const uint2*  XH   = (const uint2*)xsh;

    // prime pipeline with node k=0 state
    int degA = cnt[wid];                        // independent loads issue together
    const int2* ppA = pkw + (size_t)wid * CAP;
    int2  mcA  = ppA[o4];
    float skbA = sk[wid * NB + b];
    float sqA  = sq[(mcA.x & 16383) * NB + b];  // dependent hop

    for (int k = 0; k < KNODES; ++k) {
        int n = wid + k * NWAVES;
        if (n >= NNODES) break;
        int nn = wid + (k + 1) * NWAVES;
        bool hasN = (k + 1 < KNODES) && (nn < NNODES);

        // issue next node's INDEPENDENT loads now (hidden under this node's work)
        int degB = 0; int2 mcB = make_int2((int)NNODES, 0); float skbB = 0.f;
        const int2* ppB = pkw;
        if (hasN) {
            degB = cnt[nn];
            ppB  = pkw + (size_t)nn * CAP;
            mcB  = ppB[o4];
            skbB = sk[nn * NB + b];
        }

        int deg = min(degA, CAP - 24);          // clamp: prefetch overrun stays in-bucket
        float4 acc = {0.f, 0.f, 0.f, 0.f};
        int2 mc = mcA; float sqc = sqA;
        for (int c0 = 0; c0 < deg; c0 += 8) {
            int2 mn = ppA[c0 + 8 + o4];         // unconditional in-node prefetch
            float sqn = sq[(mn.x & 16383) * NB + b];
            float att_own = (c0 + o4 < deg)
                          ? sigmoidf_(sqc + skbA + __int_as_float(mc.y)) : 0.f;
            #pragma unroll
            for (int j = 0; j < 8; ++j) {
                int spk = __builtin_amdgcn_readlane(mc.x, j);   // SGPR: edge j metadata
                int ssrc, six;
                if (c0 + j < deg) {             // wave-uniform -> s_cselect
                    ssrc = spk & 16383;
                    six  = (spk >> 14) & 2047;
                } else {                        // masked: zero sentinel row, LUT entry 0
                    ssrc = NNODES;
                    six  = 0;
                }
                uint2 hx = XH[(size_t)ssrc * 64 + l];   // bf16 x4 (scalar base + lane l)
                uint2 hg = luth[six * 8 + o4];          // bf16 sige
                float at = __shfl(att_own, b * 8 + j);  // (edge j, this lane's b)
                acc.x += at * __uint_as_float(hg.x << 16)          * __uint_as_float(hx.x << 16);
                acc.y += at * __uint_as_float(hg.x & 0xffff0000u)  * __uint_as_float(hx.x & 0xffff0000u);
                acc.z += at * __uint_as_float(hg.y << 16)          * __uint_as_float(hx.y << 16);
                acc.w += at * __uint_as_float(hg.y & 0xffff0000u)  * __uint_as_float(hx.y & 0xffff0000u);
            }
            mc = mn; sqc = sqn;
        }

        // issue next node's DEPENDENT sq gather (mcB has arrived); epilogue covers it
        float sqB = 0.f;
        if (hasN) sqB = sq[(mcB.x & 16383) * NB + b];

        // LDS-staged epilogue (wave-local padded slices, no barrier)
        uint2 hv = XH[(size_t)n * 64 + l];
        float4 xv;
        xv.x = __uint_as_float(hv.x << 16);
        xv.y = __uint_as_float(hv.x & 0xffff0000u);
        xv.z = __uint_as_float(hv.y << 16);
        xv.w = __uint_as_float(hv.y & 0xffff0000u);
        ((float4*)&xL[w][b][0])[o4] = xv;
        ((float4*)&aL[w][b][0])[o4] = acc;
        float4 u = ((const float4*)ob)[o4];
        #pragma unroll 4
        for (int c = 0; c < NC; ++c) {
            float xc = xL[w][b][c];
            float ac = aL[w][b][c];
            float4 w1 = owL4[c * 8 + o4];
            float4 w2 = owL4[(NC + c) * 8 + o4];
            u.x += xc * w1.x + ac * w2.x;
            u.y += xc * w1.y + ac * w2.y;
            u.z += xc * w1.z + ac * w2.z;
            u.w += xc * w1.w + ac * w2.w;
        }
        float4 r;
        r.x = xv.x + u.x; r.y = xv.y + u.y; r.z = xv.z + u.z; r.w = xv.w + u.w;
        r.x = (r.x > 0.f) ? r.x : NEG_SLOPE * r.x;
        r.y = (r.y > 0.f) ? r.y : NEG_SLOPE * r.y;
        r.z = (r.z > 0.f) ? r.z : NEG_SLOPE * r.z;
        r.w = (r.w > 0.f) ? r.w : NEG_SLOPE * r.w;

        if (MODE == 1) {
            ((float4*)outp)[((size_t)b * NNODES + n) * 8 + o4] = r;
        } else {
            // fused layer-2 node transform: xs2h = bf16(h @ Wn2) ; sq2, sk2 (f32)
            ((float4*)&xL[w][b][0])[o4] = r;    // reuse slice (wave-local)
            float4 a2 = {0.f, 0.f, 0.f, 0.f};
            #pragma unroll 4
            for (int c = 0; c < NC; ++c) {
                float hc = xL[w][b][c];
                float4 w0 = wnL4[c * 8 + o4];
                a2.x += hc * w0.x;
                a2.y += hc * w0.y;
                a2.z += hc * w0.z;
                a2.w += hc * w0.w;
            }
            ((uint2*)xs2h)[(size_t)n * 64 + l] = make_uint2(pk2bf(a2.x, a2.y), pk2bf(a2.z, a2.w));
            float4 aqv = ((const float4*)(consts + 64))[o4];
            float4 akv = ((const float4*)(consts + 96))[o4];
            float vq = a2.x*aqv.x + a2.y*aqv.y + a2.z*aqv.z + a2.w*aqv.w;
            float vk = a2.x*akv.x + a2.y*akv.y + a2.z*akv.z + a2.w*akv.w;
            #pragma unroll
            for (int m = 4; m >= 1; m >>= 1) {
                vq += __shfl_xor(vq, m);
                vk += __shfl_xor(vk, m);
            }
            if (o4 == 0) {
                sq2[n * NB + b] = vq;
                sk2[n * NB + b] = vk;
            }
        }

        // rotate pipeline state
        degA = degB; ppA = ppB; mcA = mcB; skbA = skbB; sqA = sqB;
    }
}

extern "C" void kernel_launch(void* const* d_in, const int* in_sizes, int n_in,
                              void* d_out, int out_size, void* d_ws, size_t ws_size,
                              hipStream_t stream) {
    const float* X    = (const float*)d_in[0];
    const int*   ei0  = (const int*)  d_in[1];
    const int*   ei1  = (const int*)  d_in[2];
    const float* ew0  = (const float*)d_in[3];
    const float* ew1  = (const float*)d_in[4];
    const float* Wn1  = (const float*)d_in[7];
    const float* We1  = (const float*)d_in[8];
    const float* Q1   = (const float*)d_in[9];
    const float* K1   = (const float*)d_in[10];
    const float* aw1  = (const float*)d_in[11];
    const float* ab1  = (const float*)d_in[12];
    const float* ow1  = (const float*)d_in[13];
    const float* ob1  = (const float*)d_in[14];
    const float* Wn2  = (const float*)d_in[15];
    const float* We2  = (const float*)d_in[16];
    const float* Q2   = (const float*)d_in[17];
    const float* K2   = (const float*)d_in[18];
    const float* aw2  = (const float*)d_in[19];
    const float* ab2  = (const float*)d_in[20];
    const float* ow2  = (const float*)d_in[21];
    const float* ob2  = (const float*)d_in[22];

    const size_t ROWH = (size_t)(NNODES + 1) * 128;      // u32 words per bf16 xs buffer
    const size_t SS   = (size_t)(NNODES + 1) * NB;       // 80,008
    unsigned* XS1H  = (unsigned*)d_ws;
    unsigned* XS2H  = XS1H + ROWH;
    float* SQ1    = (float*)(XS2H + ROWH);
    float* SK1    = SQ1 + SS;
    float* SQ2    = SK1 + SS;
    float* SK2    = SQ2 + SS;
    float* CONSTS = SK2 + SS;                            // 160
    uint2* LUTH   = (uint2*)(CONSTS + 160);              // 2*LUTB*8 uint2 (256 KB)
    int*   CNT    = (int*)(LUTH + 2 * LUTB * 8);         // 2*N
    int2*  PKW1   = (int2*)(CNT + 2 * NNODES);
    int2*  PKW2   = PKW1 + (size_t)NNODES * CAP;

    hipMemsetAsync(CNT, 0, 2 * NNODES * sizeof(int), stream);
    prologue_kernel<<<2 * EBLKS + LUTBLKS + 1 + NNODES / 4, 256, 0, stream>>>(
        Q1, K1, aw1, We1, Q2, K2, aw2, We2, ei0, ei1, ew0, ew1, ab1, ab2,
        CONSTS, LUTH, PKW1, PKW2, CNT, XS1H, XS2H, SQ1, SK1, X, Wn1);

    gather_kernel<0><<<NWAVES / 4, 256, 0, stream>>>(
        CNT, PKW1, XS1H, SQ1, SK1, LUTH, CONSTS,
        ow1, ob1, Wn2, XS2H, SQ2, SK2, nullptr);
    gather_kernel<1><<<NWAVES / 4, 256, 0, stream>>>(
        CNT + NNODES, PKW2, XS2H, SQ2, SK2, LUTH + LUTB * 8, CONSTS,
        ow2, ob2, nullptr, nullptr, nullptr, nullptr, (float*)d_out);
}

// Round 21
// 87.374 us; speedup vs baseline: 1.3013x; 1.0171x over previous
//
#include <hip/hip_runtime.h>

#define NNODES 10000
#define NEDGES 160000
#define NB 8
#define NC 32
#define NCP 36        // padded LDS row stride (floats): bank(b*36+c) spreads b-groups
#define CAP 96        // slots per node bucket (deg clamp 72; Poisson(16) tail ~1e-25)
#define LUTB 2048
#define EBLKS 625     // NEDGES/256 exactly
#define LUTBLKS 128   // 2*LUTB*8 uint2 entries / 256
#define NWAVES 4000   // gather waves (1000 blocks x 4); ~4 waves/SIMD resident
#define GW 1000       // gather blocks; gather<0> grid adds EBLKS scatter blocks after
#define KNODES 3      // nodes per wave, software-pipelined
constexpr float NEG_SLOPE = 0.01f;

__device__ __forceinline__ float sigmoidf_(float x) {
    return 1.0f / (1.0f + __expf(-x));
}

// pack two f32 -> one u32 holding bf16(a) in low16, bf16(b) in high16 (RNE)
__device__ __forceinline__ unsigned pk2bf(float a, float b) {
    unsigned ua = __float_as_uint(a);
    ua = (ua + 0x7fffu + ((ua >> 16) & 1u)) >> 16;
    unsigned ub = __float_as_uint(b);
    ub = (ub + 0x7fffu + ((ub >> 16) & 1u)) & 0xffff0000u;
    return ua | ub;
}

// ---- K1 (prologue; LAYER-1 work only — layer-2 scatter rides in gather<0>'s grid) ----
// [0, EBLKS)        : layer-1 edge scatter -> fixed-cap buckets (src|ix<<14, w*ce1+ab1)
// [E, E+LUTBLKS)    : bf16 sige LUT fill (both layers) + zero xs sentinel rows
// E+LUTBLKS         : consts fold ([64:96) aq2, [96:128) ak2)
// rest (NNODES/4)   : layer-1 node transform -> bf16 xs1 (inline aq/ak fold)
// cnt (2*NNODES ints) must be zeroed before this kernel.
__global__ __launch_bounds__(256) void prologue_kernel(
    const float* Q1, const float* K1, const float* aw1, const float* We1,
    const float* Q2, const float* K2, const float* aw2, const float* We2,
    const int* __restrict__ ei0, const float* __restrict__ ew0,
    const float* __restrict__ ab1,
    float* consts, uint2* __restrict__ lut,
    int2* __restrict__ pkw1,
    int* __restrict__ cnt,
    unsigned* __restrict__ xs1h, unsigned* __restrict__ xs2h,
    float* __restrict__ sq1, float* __restrict__ sk1,
    const float* __restrict__ X, const float* __restrict__ Wn)
{
    int bx = blockIdx.x;
    int t = threadIdx.x;

    if (bx < EBLKS) {                           // layer-1 scatter (no tail: 160000%256==0)
        __shared__ float sCE, sAB;
        int e = bx * 256 + t;
        int src = ei0[e];
        int dst = ei0[NEDGES + e];
        float w = ew0[e];
        if (t < 32) {                           // per-block ce1 = We1 . aw1[64:96], ab1
            float p = We1[t] * aw1[64 + t];
            #pragma unroll
            for (int m = 16; m >= 1; m >>= 1) p += __shfl_xor(p, m, 32);
            if (t == 0) { sCE = p; sAB = ab1[0]; }
        }
        __syncthreads();
        int pos = atomicAdd(&cnt[dst], 1);
        if (pos < CAP) {
            int ix = (int)(w * (float)LUTB);
            ix = min(max(ix, 0), LUTB - 1);
            pkw1[(size_t)dst * CAP + pos] =
                make_int2(src | (ix << 14), __float_as_int(w * sCE + sAB));
        }
        return;
    }
    if (bx < EBLKS + LUTBLKS) {                 // bf16 sige LUT [2][2048][8 uint2]
        int i = (bx - EBLKS) * 256 + t;         // uint2 entry index
        int layer = i >> 14;                    // LUTB*8 = 16384
        int bin   = (i >> 3) & (LUTB - 1);
        int o4    = i & 7;
        float w   = (bin + 0.5f) * (1.0f / LUTB);
        const float* We = layer ? We2 : We1;
        float s0 = sigmoidf_(w * We[o4 * 4 + 0]);
        float s1 = sigmoidf_(w * We[o4 * 4 + 1]);
        float s2 = sigmoidf_(w * We[o4 * 4 + 2]);
        float s3 = sigmoidf_(w * We[o4 * 4 + 3]);
        lut[i] = make_uint2(pk2bf(s0, s1), pk2bf(s2, s3));
        if (i < 128) {                          // zero bf16 xs sentinel rows (row NNODES)
            xs1h[(size_t)NNODES * 128 + i] = 0u;
            xs2h[(size_t)NNODES * 128 + i] = 0u;
        }
        return;
    }
    if (bx == EBLKS + LUTBLKS) {                // consts fold (layer-2 aq/ak only)
        if (t < 32) {
            float aq2 = 0.f, ak2 = 0.f;
            for (int s = 0; s < 32; ++s) {
                aq2 += Q2[t * 32 + s] * aw2[s];
                ak2 += K2[t * 32 + s] * aw2[32 + s];
            }
            consts[64 + t] = aq2;
            consts[96 + t] = ak2;
        }
        return;
    }

    // node transform: xs1h = bf16(X @ Wn) ; sq1 = xs.aq ; sk1 = xs.ak (X is [B,N,C])
    __shared__ float wnL[NC * NC];
    __shared__ float aqL[NC], akL[NC];
    __shared__ float xrow[4][NB][NC + 4];
    int w = t >> 6, l = t & 63, b = l >> 3, o4 = l & 7;
    int n = (bx - (EBLKS + LUTBLKS + 1)) * 4 + w;
    for (int i = t; i < NC * NC; i += 256) wnL[i] = Wn[i];
    if (t < 64) {                               // inline aq/ak fold (no cross-block dep)
        int which = t >> 5, o = t & 31;
        const float* M  = which ? K1 : Q1;
        const float* av = aw1 + which * 32;
        float s = 0.f;
        for (int k = 0; k < 32; ++k) s += M[o * 32 + k] * av[k];
        (which ? akL : aqL)[o] = s;
    }
    const float4* X4 = (const float4*)X;
    float4 xv = X4[((size_t)b * NNODES + n) * 8 + o4];
    ((float4*)&xrow[w][b][0])[o4] = xv;
    __syncthreads();
    float4 aq = ((const float4*)aqL)[o4];
    float4 ak = ((const float4*)akL)[o4];
    const float4* wnL4 = (const float4*)wnL;
    float4 acc = {0.f, 0.f, 0.f, 0.f};
    #pragma unroll
    for (int c = 0; c < NC; ++c) {
        float xc = xrow[w][b][c];
        float4 w4 = wnL4[c * 8 + o4];
        acc.x += xc * w4.x; acc.y += xc * w4.y;
        acc.z += xc * w4.z; acc.w += xc * w4.w;
    }
    ((uint2*)xs1h)[(size_t)n * 64 + l] = make_uint2(pk2bf(acc.x, acc.y), pk2bf(acc.z, acc.w));
    float vq = acc.x * aq.x + acc.y * aq.y + acc.z * aq.z + acc.w * aq.w;
    float vk = acc.x * ak.x + acc.y * ak.y + acc.z * ak.z + acc.w * ak.w;
    #pragma unroll
    for (int m = 4; m >= 1; m >>= 1) {
        vq += __shfl_xor(vq, m);
        vk += __shfl_xor(vk, m);
    }
    if (o4 == 0) {
        sq1[n * NB + b] = vq;
        sk1[n * NB + b] = vk;
    }
}

// Gather (R18/R20 structure): 1000 gather blocks x 4 waves, wave wid handles nodes
// wid + k*NWAVES (k<KNODES), software-pipelined across nodes. Padded LDS slices.
// MODE 0: blocks [GW, GW+EBLKS) additionally run the LAYER-2 SCATTER concurrently
// (gather<1>'s only prologue dependency) — fills idle issue slots of the
// latency-bound gather waves instead of serializing in K1.
// MODE 0 epilogue fuses the layer-2 node transform; MODE 1 writes [B,N,C] f32.
template <int MODE>
__global__ __launch_bounds__(256) void gather_kernel(
    const int* __restrict__ cnt, const int2* __restrict__ pkw,
    const unsigned* __restrict__ xsh,
    const float* __restrict__ sq, const float* __restrict__ sk,
    const uint2* __restrict__ luth,
    const float* __restrict__ consts,
    const float* __restrict__ ow, const float* __restrict__ ob,
    const float* __restrict__ Wn2,
    unsigned* __restrict__ xs2h, float* __restrict__ sq2, float* __restrict__ sk2,
    float* __restrict__ outp,
    const int* __restrict__ ei1, const float* __restrict__ ew1,
    const float* __restrict__ ab2, const float* __restrict__ aw2,
    const float* __restrict__ We2,
    int* __restrict__ cnt2, int2* __restrict__ pkw2)
{
    int t = threadIdx.x;

    if (MODE == 0 && blockIdx.x >= GW) {        // layer-2 scatter (concurrent w/ gather)
        __shared__ float sCE, sAB;
        int e = (blockIdx.x - GW) * 256 + t;
        int src = ei1[e];
        int dst = ei1[NEDGES + e];
        float w = ew1[e];
        if (t < 32) {                           // per-block ce2 = We2 . aw2[64:96], ab2
            float p = We2[t] * aw2[64 + t];
            #pragma unroll
            for (int m = 16; m >= 1; m >>= 1) p += __shfl_xor(p, m, 32);
            if (t == 0) { sCE = p; sAB = ab2[0]; }
        }
        __syncthreads();
        int pos = atomicAdd(&cnt2[dst], 1);
        if (pos < CAP) {
            int ix = (int)(w * (float)LUTB);
            ix = min(max(ix, 0), LUTB - 1);
            pkw2[(size_t)dst * CAP + pos] =
                make_int2(src | (ix << 14), __float_as_int(w * sCE + sAB));
        }
        return;
    }

    __shared__ __align__(16) float owL[2 * NC * NC];                 // 8 KB
    __shared__ __align__(16) float wnL[(MODE == 0) ? NC * NC : 4];   // 4 KB (MODE 0)
    __shared__ __align__(16) float xL[4][NB][NCP];                   // padded slices
    __shared__ __align__(16) float aL[4][NB][NCP];

    int w = t >> 6, l = t & 63, b = l >> 3, o4 = l & 7;
    int wid = blockIdx.x * 4 + w;
    for (int i = t; i < 2 * NC * NC; i += 256) owL[i] = ow[i];
    if (MODE == 0)
        for (int i = t; i < NC * NC; i += 256) wnL[i] = Wn2[i];
    __syncthreads();   // only barrier (weight staging)

    const float4* owL4 = (const float4*)owL;
    const float4* wnL4 = (const float4*)wnL;
    const uint2*  XH   = (const uint2*)xsh;

    // prime pipeline with node k=0 state
    int degA = cnt[wid];                        // independent loads issue together
    const int2* ppA = pkw + (size_t)wid * CAP;
    int2  mcA  = ppA[o4];
    float skbA = sk[wid * NB + b];
    float sqA  = sq[(mcA.x & 16383) * NB + b];  // dependent hop

    for (int k = 0; k < KNODES; ++k) {
        int n = wid + k * NWAVES;
        if (n >= NNODES) break;
        int nn = wid + (k + 1) * NWAVES;
        bool hasN = (k + 1 < KNODES) && (nn < NNODES);

        // issue next node's INDEPENDENT loads now (hidden under this node's work)
        int degB = 0; int2 mcB = make_int2((int)NNODES, 0); float skbB = 0.f;
        const int2* ppB = pkw;
        if (hasN) {
            degB = cnt[nn];
            ppB  = pkw + (size_t)nn * CAP;
            mcB  = ppB[o4];
            skbB = sk[nn * NB + b];
        }

        int deg = min(degA, CAP - 24);          // clamp: prefetch overrun stays in-bucket
        float4 acc = {0.f, 0.f, 0.f, 0.f};
        int2 mc = mcA; float sqc = sqA;
        for (int c0 = 0; c0 < deg; c0 += 8) {
            int2 mn = ppA[c0 + 8 + o4];         // unconditional in-node prefetch
            float sqn = sq[(mn.x & 16383) * NB + b];
            float att_own = (c0 + o4 < deg)
                          ? sigmoidf_(sqc + skbA + __int_as_float(mc.y)) : 0.f;
            #pragma unroll
            for (int j = 0; j < 8; ++j) {
                int spk = __builtin_amdgcn_readlane(mc.x, j);   // SGPR: edge j metadata
                int ssrc, six;
                if (c0 + j < deg) {             // wave-uniform -> s_cselect
                    ssrc = spk & 16383;
                    six  = (spk >> 14) & 2047;
                } else {                        // masked: zero sentinel row, LUT entry 0
                    ssrc = NNODES;
                    six  = 0;
                }
                uint2 hx = XH[(size_t)ssrc * 64 + l];   // bf16 x4 (scalar base + lane l)
                uint2 hg = luth[six * 8 + o4];          // bf16 sige
                float at = __shfl(att_own, b * 8 + j);  // (edge j, this lane's b)
                acc.x += at * __uint_as_float(hg.x << 16)          * __uint_as_float(hx.x << 16);
                acc.y += at * __uint_as_float(hg.x & 0xffff0000u)  * __uint_as_float(hx.x & 0xffff0000u);
                acc.z += at * __uint_as_float(hg.y << 16)          * __uint_as_float(hx.y << 16);
                acc.w += at * __uint_as_float(hg.y & 0xffff0000u)  * __uint_as_float(hx.y & 0xffff0000u);
            }
            mc = mn; sqc = sqn;
        }

        // issue next node's DEPENDENT sq gather (mcB has arrived); epilogue covers it
        float sqB = 0.f;
        if (hasN) sqB = sq[(mcB.x & 16383) * NB + b];

        // LDS-staged epilogue (wave-local padded slices, no barrier)
        uint2 hv = XH[(size_t)n * 64 + l];
        float4 xv;
        xv.x = __uint_as_float(hv.x << 16);
        xv.y = __uint_as_float(hv.x & 0xffff0000u);
        xv.z = __uint_as_float(hv.y << 16);
        xv.w = __uint_as_float(hv.y & 0xffff0000u);
        ((float4*)&xL[w][b][0])[o4] = xv;
        ((float4*)&aL[w][b][0])[o4] = acc;
        float4 u = ((const float4*)ob)[o4];
        #pragma unroll 4
        for (int c = 0; c < NC; ++c) {
            float xc = xL[w][b][c];
            float ac = aL[w][b][c];
            float4 w1 = owL4[c * 8 + o4];
            float4 w2 = owL4[(NC + c) * 8 + o4];
            u.x += xc * w1.x + ac * w2.x;
            u.y += xc * w1.y + ac * w2.y;
            u.z += xc * w1.z + ac * w2.z;
            u.w += xc * w1.w + ac * w2.w;
        }
        float4 r;
        r.x = xv.x + u.x; r.y = xv.y + u.y; r.z = xv.z + u.z; r.w = xv.w + u.w;
        r.x = (r.x > 0.f) ? r.x : NEG_SLOPE * r.x;
        r.y = (r.y > 0.f) ? r.y : NEG_SLOPE * r.y;
        r.z = (r.z > 0.f) ? r.z : NEG_SLOPE * r.z;
        r.w = (r.w > 0.f) ? r.w : NEG_SLOPE * r.w;

        if (MODE == 1) {
            ((float4*)outp)[((size_t)b * NNODES + n) * 8 + o4] = r;
        } else {
            // fused layer-2 node transform: xs2h = bf16(h @ Wn2) ; sq2, sk2 (f32)
            ((float4*)&xL[w][b][0])[o4] = r;    // reuse slice (wave-local)
            float4 a2 = {0.f, 0.f, 0.f, 0.f};
            #pragma unroll 4
            for (int c = 0; c < NC; ++c) {
                float hc = xL[w][b][c];
                float4 w0 = wnL4[c * 8 + o4];
                a2.x += hc * w0.x;
                a2.y += hc * w0.y;
                a2.z += hc * w0.z;
                a2.w += hc * w0.w;
            }
            ((uint2*)xs2h)[(size_t)n * 64 + l] = make_uint2(pk2bf(a2.x, a2.y), pk2bf(a2.z, a2.w));
            float4 aqv = ((const float4*)(consts + 64))[o4];
            float4 akv = ((const float4*)(consts + 96))[o4];
            float vq = a2.x*aqv.x + a2.y*aqv.y + a2.z*aqv.z + a2.w*aqv.w;
            float vk = a2.x*akv.x + a2.y*akv.y + a2.z*akv.z + a2.w*akv.w;
            #pragma unroll
            for (int m = 4; m >= 1; m >>= 1) {
                vq += __shfl_xor(vq, m);
                vk += __shfl_xor(vk, m);
            }
            if (o4 == 0) {
                sq2[n * NB + b] = vq;
                sk2[n * NB + b] = vk;
            }
        }

        // rotate pipeline state
        degA = degB; ppA = ppB; mcA = mcB; skbA = skbB; sqA = sqB;
    }
}

extern "C" void kernel_launch(void* const* d_in, const int* in_sizes, int n_in,
                              void* d_out, int out_size, void* d_ws, size_t ws_size,
                              hipStream_t stream) {
    const float* X    = (const float*)d_in[0];
    const int*   ei0  = (const int*)  d_in[1];
    const int*   ei1  = (const int*)  d_in[2];
    const float* ew0  = (const float*)d_in[3];
    const float* ew1  = (const float*)d_in[4];
    const float* Wn1  = (const float*)d_in[7];
    const float* We1  = (const float*)d_in[8];
    const float* Q1   = (const float*)d_in[9];
    const float* K1   = (const float*)d_in[10];
    const float* aw1  = (const float*)d_in[11];
    const float* ab1  = (const float*)d_in[12];
    const float* ow1  = (const float*)d_in[13];
    const float* ob1  = (const float*)d_in[14];
    const float* Wn2  = (const float*)d_in[15];
    const float* We2  = (const float*)d_in[16];
    const float* Q2   = (const float*)d_in[17];
    const float* K2   = (const float*)d_in[18];
    const float* aw2  = (const float*)d_in[19];
    const float* ab2  = (const float*)d_in[20];
    const float* ow2  = (const float*)d_in[21];
    const float* ob2  = (const float*)d_in[22];

    const size_t ROWH = (size_t)(NNODES + 1) * 128;      // u32 words per bf16 xs buffer
    const size_t SS   = (size_t)(NNODES + 1) * NB;       // 80,008
    unsigned* XS1H  = (unsigned*)d_ws;
    unsigned* XS2H  = XS1H + ROWH;
    float* SQ1    = (float*)(XS2H + ROWH);
    float* SK1    = SQ1 + SS;
    float* SQ2    = SK1 + SS;
    float* SK2    = SQ2 + SS;
    float* CONSTS = SK2 + SS;                            // 160
    uint2* LUTH   = (uint2*)(CONSTS + 160);              // 2*LUTB*8 uint2 (256 KB)
    int*   CNT    = (int*)(LUTH + 2 * LUTB * 8);         // 2*N
    int2*  PKW1   = (int2*)(CNT + 2 * NNODES);
    int2*  PKW2   = PKW1 + (size_t)NNODES * CAP;

    hipMemsetAsync(CNT, 0, 2 * NNODES * sizeof(int), stream);
    prologue_kernel<<<EBLKS + LUTBLKS + 1 + NNODES / 4, 256, 0, stream>>>(
        Q1, K1, aw1, We1, Q2, K2, aw2, We2, ei0, ew0, ab1,
        CONSTS, LUTH, PKW1, CNT, XS1H, XS2H, SQ1, SK1, X, Wn1);

    gather_kernel<0><<<GW + EBLKS, 256, 0, stream>>>(
        CNT, PKW1, XS1H, SQ1, SK1, LUTH, CONSTS,
        ow1, ob1, Wn2, XS2H, SQ2, SK2, nullptr,
        ei1, ew1, ab2, aw2, We2, CNT + NNODES, PKW2);
    gather_kernel<1><<<GW, 256, 0, stream>>>(
        CNT + NNODES, PKW2, XS2H, SQ2, SK2, LUTH + LUTB * 8, CONSTS,
        ow2, ob2, nullptr, nullptr, nullptr, nullptr, (float*)d_out,
        nullptr, nullptr, nullptr, nullptr, nullptr, nullptr, nullptr);
}